// Round 11
// baseline (358.938 us; speedup 1.0000x reference)
//
#include <hip/hip_runtime.h>
#include <math.h>

#define BB 64
#define LL 200
#define DD 128
#define MM 50
#define NQ 10000
#define NPOS (BB * LL)   // 12800
#define LC 20            // scan chunk length
#define NC 10            // number of chunks (LC*NC == LL)

#define REP_SCANA 16     // diagnostic amplification (idempotent)

__device__ __forceinline__ float dot4(float4 a, float4 b, float c) {
    return fmaf(a.x, b.x, fmaf(a.y, b.y, fmaf(a.z, b.z, fmaf(a.w, b.w, c))));
}

// ---------------------------------------------------------------------------
// Kernel 1 (fused dispatch): blocks 0..199 -> w = softmax(k@Mk^T) (64 pos,
// lane = position, wave owns 13 m-rows); blocks 200..999 -> e/a (64 pos x
// 4 i-chunks, wave owns 8 output dims). Both R8-measured-best bodies.
// ---------------------------------------------------------------------------
__global__ __launch_bounds__(256) void k_wea2(
    const int* __restrict__ q, const int* __restrict__ r,
    const float* __restrict__ k_emb, const float* __restrict__ v_emb,
    const float* __restrict__ Mk,
    const float* __restrict__ e_W, const float* __restrict__ e_b,
    const float* __restrict__ a_W, const float* __restrict__ a_b,
    float* __restrict__ w_ws, float* __restrict__ e_ws, float* __restrict__ a_ws)
{
    __shared__ float smem[11668];

    const int tid  = threadIdx.x;
    const int w    = tid >> 6;
    const int lane = tid & 63;

    if (blockIdx.x < 200) {
        // ================= k_w role =================
        float* kv = smem;                 // [64][129]
        float* lg = smem + 8256;          // [64][53]
        const int p0 = blockIdx.x * 64;

        #pragma unroll
        for (int it = 0; it < 8; ++it) {
            int idx = it * 256 + tid;            // 64 pos x 32 float4
            int pos = idx >> 5, c4 = idx & 31;
            float4 kk = *(const float4*)(k_emb + (size_t)q[p0 + pos] * DD + c4 * 4);
            float* dst = &kv[pos * 129 + c4 * 4];
            dst[0] = kk.x; dst[1] = kk.y; dst[2] = kk.z; dst[3] = kk.w;
        }
        __syncthreads();

        {
            const int m0 = __builtin_amdgcn_readfirstlane(w < 3 ? w * 13 : 37);
            const float4* MkR = (const float4*)Mk + (size_t)m0 * 32;
            float acc[13];
            #pragma unroll
            for (int s = 0; s < 13; ++s) acc[s] = 0.f;
            for (int j4 = 0; j4 < 32; ++j4) {
                const float* kp = &kv[lane * 129 + j4 * 4];
                float4 k4 = {kp[0], kp[1], kp[2], kp[3]};
                #pragma unroll
                for (int s = 0; s < 13; ++s)
                    acc[s] = dot4(k4, MkR[s * 32 + j4], acc[s]);
            }
            #pragma unroll
            for (int s = 0; s < 13; ++s)
                lg[lane * 53 + m0 + s] = acc[s];
        }
        __syncthreads();

        if (tid < 64) {
            float* row = &lg[tid * 53];
            float mx = -INFINITY;
            for (int m = 0; m < MM; ++m) mx = fmaxf(mx, row[m]);
            float sum = 0.f;
            for (int m = 0; m < MM; ++m) {
                float e_ = expf(row[m] - mx);
                row[m] = e_;
                sum += e_;
            }
            row[50] = 1.f / sum;
        }
        __syncthreads();

        for (int idx = tid; idx < 64 * MM; idx += 256) {
            int pos = idx / MM, m = idx - pos * MM;
            w_ws[(size_t)p0 * MM + idx] = lg[pos * 53 + m] * lg[pos * 53 + 50];
        }
    } else {
        // ================= k_ea role =================
        float* vl  = smem;                       // [64][129]
        float (*buf)[64][9] = (float (*)[64][9])(smem + 8256);

        const int bid = blockIdx.x - 200;
        const int pg  = bid >> 2;
        const int ic  = bid & 3;
        const int p0  = pg * 64;

        #pragma unroll
        for (int it = 0; it < 8; ++it) {
            int idx = it * 256 + tid;
            int pos = idx >> 5, c4 = idx & 31;
            int gp  = p0 + pos;
            int xi  = q[gp] + NQ * r[gp];
            float4 vv = *(const float4*)(v_emb + (size_t)xi * DD + c4 * 4);
            float* dst = &vl[pos * 129 + c4 * 4];
            dst[0] = vv.x; dst[1] = vv.y; dst[2] = vv.z; dst[3] = vv.w;
        }
        __syncthreads();

        const int i0 = __builtin_amdgcn_readfirstlane(ic * 32 + w * 8);
        const float4* eW4 = (const float4*)e_W + (size_t)i0 * 32;
        const float4* aW4 = (const float4*)a_W + (size_t)i0 * 32;

        float accE[8], accA[8];
        #pragma unroll
        for (int ii = 0; ii < 8; ++ii) { accE[ii] = 0.f; accA[ii] = 0.f; }

        for (int j4 = 0; j4 < 32; ++j4) {
            const float* vp = &vl[lane * 129 + j4 * 4];
            float4 v4 = {vp[0], vp[1], vp[2], vp[3]};
            #pragma unroll
            for (int ii = 0; ii < 8; ++ii) {
                accE[ii] = dot4(v4, eW4[ii * 32 + j4], accE[ii]);
                accA[ii] = dot4(v4, aW4[ii * 32 + j4], accA[ii]);
            }
        }

        #pragma unroll
        for (int ii = 0; ii < 8; ++ii)
            buf[w][lane][ii] = 1.f / (1.f + expf(-(accE[ii] + e_b[i0 + ii])));
        #pragma unroll
        for (int it = 0; it < 2; ++it) {
            int idx = it * 64 + lane;            // 64 pos x 2 q4
            int pp = idx >> 1, q4 = idx & 1;
            const float* bp = &buf[w][pp][q4 * 4];
            float4 o = {bp[0], bp[1], bp[2], bp[3]};
            *(float4*)(e_ws + (size_t)(p0 + pp) * DD + i0 + q4 * 4) = o;
        }
        #pragma unroll
        for (int ii = 0; ii < 8; ++ii)
            buf[w][lane][ii] = tanhf(accA[ii] + a_b[i0 + ii]);
        #pragma unroll
        for (int it = 0; it < 2; ++it) {
            int idx = it * 64 + lane;
            int pp = idx >> 1, q4 = idx & 1;
            const float* bp = &buf[w][pp][q4 * 4];
            float4 o = {bp[0], bp[1], bp[2], bp[3]};
            *(float4*)(a_ws + (size_t)(p0 + pp) * DD + i0 + q4 * 4) = o;
        }
    }
}

// ---------------------------------------------------------------------------
// Kernel 2a: per (b, chunk) affine composite S_out = A*S_in + B per (m,d).
// Amplified x16 this round for counter capture.
// ---------------------------------------------------------------------------
__global__ __launch_bounds__(512) void k_scanA(
    const float* __restrict__ w_ws, const float* __restrict__ e_ws,
    const float* __restrict__ a_ws,
    float* __restrict__ A_ws, float* __restrict__ B_ws, int rep)
{
    __shared__ float w_lds[LC * MM];   // 4 KB

    const int b   = blockIdx.x / NC;
    const int c   = blockIdx.x % NC;
    const int tid = threadIdx.x;
    const int d   = tid & 127;
    const int g   = tid >> 7;
    int moff = g * 13; if (g == 3) moff = 38;
    const int mcnt = (g < 2) ? 13 : 12;

    for (int rp = 0; rp < rep; ++rp) {

    const float* wsrc = w_ws + ((size_t)b * LL + c * LC) * MM;  // contiguous
    for (int idx = tid; idx < LC * MM; idx += 512) w_lds[idx] = wsrc[idx];
    __syncthreads();

    float A[13], Bv[13];
    #pragma unroll
    for (int mi = 0; mi < 13; ++mi) { A[mi] = 1.f; Bv[mi] = 0.f; }

    for (int ll = 0; ll < LC; ++ll) {
        const int gp = b * LL + c * LC + ll;
        const float e = e_ws[(size_t)gp * DD + d];
        const float a = a_ws[(size_t)gp * DD + d];
        const float* wl = w_lds + ll * MM + moff;
        #pragma unroll
        for (int mi = 0; mi < 13; ++mi) {
            if (mi < mcnt) {
                float w_ = wl[mi];
                float cc = fmaf(-w_, e, 1.f);
                A[mi] *= cc;
                Bv[mi] = fmaf(Bv[mi], cc, w_ * a);
            }
        }
    }

    float* Ao = A_ws + ((size_t)b * NC + c) * MM * DD + (size_t)moff * DD + d;
    float* Bo = B_ws + ((size_t)b * NC + c) * MM * DD + (size_t)moff * DD + d;
    #pragma unroll
    for (int mi = 0; mi < 13; ++mi) {
        if (mi < mcnt) { Ao[mi * DD] = A[mi]; Bo[mi * DD] = Bv[mi]; }
    }
    __syncthreads();
    }
}

// ---------------------------------------------------------------------------
// Kernel 2b: sequential composition over chunks; entry states in-place.
// ---------------------------------------------------------------------------
__global__ __launch_bounds__(256) void k_scanB(
    const float* __restrict__ Mv0,
    float* __restrict__ A_ws,            // in: A, out: Sentry
    const float* __restrict__ B_ws)
{
    const int g  = blockIdx.x * 256 + threadIdx.x;   // 0 .. B*M*D-1
    const int d  = g & (DD - 1);
    const int md = g >> 7;
    const int m  = md % MM;
    const int b  = md / MM;

    float S = Mv0[m * DD + d];
    const size_t base = ((size_t)b * NC * MM + m) * DD + d;
    #pragma unroll
    for (int c = 0; c < NC; ++c) {
        const size_t off = base + (size_t)c * MM * DD;
        const float Ac = A_ws[off];
        const float Bc = B_ws[off];
        A_ws[off] = S;                     // entry state of chunk c
        S = fmaf(Ac, S, Bc);
    }
}

// ---------------------------------------------------------------------------
// Kernel 2c: replay scan per (b, chunk); writes all Mv states and read.
// ---------------------------------------------------------------------------
__global__ __launch_bounds__(512) void k_scanC(
    const float* __restrict__ Sentry,     // == A_ws after k_scanB
    const float* __restrict__ w_ws, const float* __restrict__ e_ws,
    const float* __restrict__ a_ws,
    float* __restrict__ read_ws, float* __restrict__ out_Mv)
{
    __shared__ float w_lds[LC * MM];      // 4 KB
    __shared__ float red[2][4][DD];       // 4 KB

    const int b   = blockIdx.x / NC;
    const int c   = blockIdx.x % NC;
    const int tid = threadIdx.x;
    const int d   = tid & 127;
    const int g   = tid >> 7;
    int moff = g * 13; if (g == 3) moff = 38;
    const int mcnt = (g < 2) ? 13 : 12;

    const float* wsrc = w_ws + ((size_t)b * LL + c * LC) * MM;
    for (int idx = tid; idx < LC * MM; idx += 512) w_lds[idx] = wsrc[idx];

    float S[13];
    const float* Sp = Sentry + ((size_t)b * NC + c) * MM * DD + (size_t)moff * DD + d;
    #pragma unroll
    for (int mi = 0; mi < 13; ++mi)
        if (mi < mcnt) S[mi] = Sp[mi * DD];

    float* outb = out_Mv + (size_t)b * (LL + 1) * MM * DD;
    if (c == 0) {
        #pragma unroll
        for (int mi = 0; mi < 13; ++mi)
            if (mi < mcnt) outb[(moff + mi) * DD + d] = S[mi];  // init state
    }
    __syncthreads();

    for (int ll = 0; ll < LC; ++ll) {
        const int l  = c * LC + ll;
        const int gp = b * LL + l;
        const float e = e_ws[(size_t)gp * DD + d];
        const float a = a_ws[(size_t)gp * DD + d];
        const float* wl = w_lds + ll * MM + moff;

        float racc = 0.f;
        float* o = outb + (size_t)(l + 1) * MM * DD + d;
        #pragma unroll
        for (int mi = 0; mi < 13; ++mi) {
            if (mi < mcnt) {
                float w_ = wl[mi];
                racc = fmaf(w_, S[mi], racc);                // pre-update read
                S[mi] = fmaf(w_, fmaf(-S[mi], e, a), S[mi]); // S += w*(a - S*e)
                o[(moff + mi) * DD] = S[mi];
            }
        }
        red[ll & 1][g][d] = racc;
        __syncthreads();
        if (g == 0)
            read_ws[(size_t)gp * DD + d] =
                red[ll & 1][0][d] + red[ll & 1][1][d] +
                red[ll & 1][2][d] + red[ll & 1][3][d];
    }
}

// ---------------------------------------------------------------------------
// Kernel 3: f = tanh([read,k] @ f_W^T + f_b); p = sigmoid(f . p_W + p_b).
// One block = 16 positions, 128 threads. (R2-measured-best version)
// ---------------------------------------------------------------------------
__global__ __launch_bounds__(128) void k_fp(
    const int* __restrict__ q,
    const float* __restrict__ k_emb,
    const float* __restrict__ read_ws,
    const float* __restrict__ f_W, const float* __restrict__ f_b,
    const float* __restrict__ p_W, const float* __restrict__ p_b,
    float* __restrict__ out_p)
{
    __shared__ float cat[16][2 * DD];
    __shared__ float fv[16][DD];

    const int tid = threadIdx.x;
    const int p0  = blockIdx.x * 16;

    #pragma unroll
    for (int rr = 0; rr < 8; ++rr) {
        int idx = rr * 128 + tid;         // 0..1023 = 16 pos x 64 float4
        int pos = idx >> 6;
        int c4  = idx & 63;
        int gp  = p0 + pos;
        float4 val;
        if (c4 < 32) val = *(const float4*)(read_ws + (size_t)gp * DD + c4 * 4);
        else         val = *(const float4*)(k_emb + (size_t)q[gp] * DD + (c4 - 32) * 4);
        *(float4*)(&cat[pos][c4 * 4]) = val;
    }
    __syncthreads();

    const int i = tid;
    float acc[16];
    const float fb = f_b[i];
    #pragma unroll
    for (int p = 0; p < 16; ++p) acc[p] = fb;

    const float4* fw = (const float4*)(f_W + (size_t)i * (2 * DD));
    #pragma unroll 2
    for (int j4 = 0; j4 < 64; ++j4) {
        float4 wv = fw[j4];
        #pragma unroll
        for (int p = 0; p < 16; ++p) {
            const float* cp = &cat[p][j4 * 4];
            acc[p] = fmaf(wv.x, cp[0], acc[p]);
            acc[p] = fmaf(wv.y, cp[1], acc[p]);
            acc[p] = fmaf(wv.z, cp[2], acc[p]);
            acc[p] = fmaf(wv.w, cp[3], acc[p]);
        }
    }
    #pragma unroll
    for (int p = 0; p < 16; ++p) fv[p][i] = tanhf(acc[p]);
    __syncthreads();

    const int pos = tid >> 3;
    const int l8  = tid & 7;
    float partial = 0.f;
    #pragma unroll
    for (int ii = l8; ii < DD; ii += 8)
        partial = fmaf(fv[pos][ii], p_W[ii], partial);
    partial += __shfl_down(partial, 4, 64);
    partial += __shfl_down(partial, 2, 64);
    partial += __shfl_down(partial, 1, 64);
    if (l8 == 0)
        out_p[p0 + pos] = 1.f / (1.f + expf(-(partial + p_b[0])));
}

// ---------------------------------------------------------------------------
extern "C" void kernel_launch(void* const* d_in, const int* in_sizes, int n_in,
                              void* d_out, int out_size, void* d_ws, size_t ws_size,
                              hipStream_t stream)
{
    const int*   q     = (const int*)d_in[0];
    const int*   r     = (const int*)d_in[1];
    const float* k_emb = (const float*)d_in[2];
    const float* v_emb = (const float*)d_in[3];
    const float* Mk    = (const float*)d_in[4];
    const float* Mv0   = (const float*)d_in[5];
    const float* f_W   = (const float*)d_in[6];
    const float* f_b   = (const float*)d_in[7];
    const float* p_W   = (const float*)d_in[8];
    const float* p_b   = (const float*)d_in[9];
    const float* e_W   = (const float*)d_in[10];
    const float* e_b   = (const float*)d_in[11];
    const float* a_W   = (const float*)d_in[12];
    const float* a_b   = (const float*)d_in[13];

    float* out_p  = (float*)d_out;           // [B,L]
    float* out_Mv = out_p + NPOS;            // [B,L+1,M,D]

    float* w_ws    = (float*)d_ws;                         // NPOS*MM
    float* e_ws    = w_ws + (size_t)NPOS * MM;             // NPOS*DD
    float* a_ws    = e_ws + (size_t)NPOS * DD;             // NPOS*DD
    float* read_ws = a_ws + (size_t)NPOS * DD;             // NPOS*DD
    float* A_ws    = read_ws + (size_t)NPOS * DD;          // B*NC*MM*DD
    float* B_ws    = A_ws + (size_t)BB * NC * MM * DD;     // B*NC*MM*DD

    hipLaunchKernelGGL(k_wea2, dim3(1000), dim3(256), 0, stream,
                       q, r, k_emb, v_emb, Mk, e_W, e_b, a_W, a_b,
                       w_ws, e_ws, a_ws);
    hipLaunchKernelGGL(k_scanA, dim3(BB * NC), dim3(512), 0, stream,
                       w_ws, e_ws, a_ws, A_ws, B_ws, REP_SCANA);
    hipLaunchKernelGGL(k_scanB, dim3((BB * MM * DD) / 256), dim3(256), 0, stream,
                       Mv0, A_ws, B_ws);
    hipLaunchKernelGGL(k_scanC, dim3(BB * NC), dim3(512), 0, stream,
                       A_ws, w_ws, e_ws, a_ws, read_ws, out_Mv);
    hipLaunchKernelGGL(k_fp, dim3(NPOS / 16), dim3(128), 0, stream,
                       q, k_emb, read_ws, f_W, f_b, p_W, p_b, out_p);
}

// Round 12
// 177.699 us; speedup vs baseline: 2.0199x; 2.0199x over previous
//
#include <hip/hip_runtime.h>
#include <math.h>

#define BB 64
#define LL 200
#define DD 128
#define MM 50
#define NQ 10000
#define NPOS (BB * LL)   // 12800
#define LC 20            // scan chunk length
#define NC 10            // number of chunks (LC*NC == LL)

__device__ __forceinline__ float dot4(float4 a, float4 b, float c) {
    return fmaf(a.x, b.x, fmaf(a.y, b.y, fmaf(a.z, b.z, fmaf(a.w, b.w, c))));
}

// ---------------------------------------------------------------------------
// Kernel 1 (fused dispatch): blocks 0..199 -> w = softmax(k@Mk^T) (64 pos,
// lane = position, wave owns 13 m-rows); blocks 200..999 -> e/a (64 pos x
// 4 i-chunks, wave owns 8 output dims). Measured-best bodies (R8/R11).
// ---------------------------------------------------------------------------
__global__ __launch_bounds__(256) void k_wea2(
    const int* __restrict__ q, const int* __restrict__ r,
    const float* __restrict__ k_emb, const float* __restrict__ v_emb,
    const float* __restrict__ Mk,
    const float* __restrict__ e_W, const float* __restrict__ e_b,
    const float* __restrict__ a_W, const float* __restrict__ a_b,
    float* __restrict__ w_ws, float* __restrict__ e_ws, float* __restrict__ a_ws)
{
    __shared__ float smem[11668];

    const int tid  = threadIdx.x;
    const int w    = tid >> 6;
    const int lane = tid & 63;

    if (blockIdx.x < 200) {
        // ================= k_w role =================
        float* kv = smem;                 // [64][129]
        float* lg = smem + 8256;          // [64][53]
        const int p0 = blockIdx.x * 64;

        #pragma unroll
        for (int it = 0; it < 8; ++it) {
            int idx = it * 256 + tid;            // 64 pos x 32 float4
            int pos = idx >> 5, c4 = idx & 31;
            float4 kk = *(const float4*)(k_emb + (size_t)q[p0 + pos] * DD + c4 * 4);
            float* dst = &kv[pos * 129 + c4 * 4];
            dst[0] = kk.x; dst[1] = kk.y; dst[2] = kk.z; dst[3] = kk.w;
        }
        __syncthreads();

        {
            const int m0 = __builtin_amdgcn_readfirstlane(w < 3 ? w * 13 : 37);
            const float4* MkR = (const float4*)Mk + (size_t)m0 * 32;
            float acc[13];
            #pragma unroll
            for (int s = 0; s < 13; ++s) acc[s] = 0.f;
            for (int j4 = 0; j4 < 32; ++j4) {
                const float* kp = &kv[lane * 129 + j4 * 4];
                float4 k4 = {kp[0], kp[1], kp[2], kp[3]};
                #pragma unroll
                for (int s = 0; s < 13; ++s)
                    acc[s] = dot4(k4, MkR[s * 32 + j4], acc[s]);
            }
            #pragma unroll
            for (int s = 0; s < 13; ++s)
                lg[lane * 53 + m0 + s] = acc[s];
        }
        __syncthreads();

        if (tid < 64) {
            float* row = &lg[tid * 53];
            float mx = -INFINITY;
            for (int m = 0; m < MM; ++m) mx = fmaxf(mx, row[m]);
            float sum = 0.f;
            for (int m = 0; m < MM; ++m) {
                float e_ = expf(row[m] - mx);
                row[m] = e_;
                sum += e_;
            }
            row[50] = 1.f / sum;
        }
        __syncthreads();

        for (int idx = tid; idx < 64 * MM; idx += 256) {
            int pos = idx / MM, m = idx - pos * MM;
            w_ws[(size_t)p0 * MM + idx] = lg[pos * 53 + m] * lg[pos * 53 + 50];
        }
    } else {
        // ================= k_ea role =================
        float* vl  = smem;                       // [64][129]
        float (*buf)[64][9] = (float (*)[64][9])(smem + 8256);

        const int bid = blockIdx.x - 200;
        const int pg  = bid >> 2;
        const int ic  = bid & 3;
        const int p0  = pg * 64;

        #pragma unroll
        for (int it = 0; it < 8; ++it) {
            int idx = it * 256 + tid;
            int pos = idx >> 5, c4 = idx & 31;
            int gp  = p0 + pos;
            int xi  = q[gp] + NQ * r[gp];
            float4 vv = *(const float4*)(v_emb + (size_t)xi * DD + c4 * 4);
            float* dst = &vl[pos * 129 + c4 * 4];
            dst[0] = vv.x; dst[1] = vv.y; dst[2] = vv.z; dst[3] = vv.w;
        }
        __syncthreads();

        const int i0 = __builtin_amdgcn_readfirstlane(ic * 32 + w * 8);
        const float4* eW4 = (const float4*)e_W + (size_t)i0 * 32;
        const float4* aW4 = (const float4*)a_W + (size_t)i0 * 32;

        float accE[8], accA[8];
        #pragma unroll
        for (int ii = 0; ii < 8; ++ii) { accE[ii] = 0.f; accA[ii] = 0.f; }

        for (int j4 = 0; j4 < 32; ++j4) {
            const float* vp = &vl[lane * 129 + j4 * 4];
            float4 v4 = {vp[0], vp[1], vp[2], vp[3]};
            #pragma unroll
            for (int ii = 0; ii < 8; ++ii) {
                accE[ii] = dot4(v4, eW4[ii * 32 + j4], accE[ii]);
                accA[ii] = dot4(v4, aW4[ii * 32 + j4], accA[ii]);
            }
        }

        #pragma unroll
        for (int ii = 0; ii < 8; ++ii)
            buf[w][lane][ii] = 1.f / (1.f + expf(-(accE[ii] + e_b[i0 + ii])));
        #pragma unroll
        for (int it = 0; it < 2; ++it) {
            int idx = it * 64 + lane;            // 64 pos x 2 q4
            int pp = idx >> 1, q4 = idx & 1;
            const float* bp = &buf[w][pp][q4 * 4];
            float4 o = {bp[0], bp[1], bp[2], bp[3]};
            *(float4*)(e_ws + (size_t)(p0 + pp) * DD + i0 + q4 * 4) = o;
        }
        #pragma unroll
        for (int ii = 0; ii < 8; ++ii)
            buf[w][lane][ii] = tanhf(accA[ii] + a_b[i0 + ii]);
        #pragma unroll
        for (int it = 0; it < 2; ++it) {
            int idx = it * 64 + lane;
            int pp = idx >> 1, q4 = idx & 1;
            const float* bp = &buf[w][pp][q4 * 4];
            float4 o = {bp[0], bp[1], bp[2], bp[3]};
            *(float4*)(a_ws + (size_t)(p0 + pp) * DD + i0 + q4 * 4) = o;
        }
    }
}

// ---------------------------------------------------------------------------
// Kernel 2a: per (b, chunk) affine composite S_out = A*S_in + B per (m,d).
// (measured: ~14 µs, VALUBusy 40%, near floor)
// ---------------------------------------------------------------------------
__global__ __launch_bounds__(512) void k_scanA(
    const float* __restrict__ w_ws, const float* __restrict__ e_ws,
    const float* __restrict__ a_ws,
    float* __restrict__ A_ws, float* __restrict__ B_ws)
{
    __shared__ float w_lds[LC * MM];   // 4 KB

    const int b   = blockIdx.x / NC;
    const int c   = blockIdx.x % NC;
    const int tid = threadIdx.x;
    const int d   = tid & 127;
    const int g   = tid >> 7;
    int moff = g * 13; if (g == 3) moff = 38;
    const int mcnt = (g < 2) ? 13 : 12;

    const float* wsrc = w_ws + ((size_t)b * LL + c * LC) * MM;  // contiguous
    for (int idx = tid; idx < LC * MM; idx += 512) w_lds[idx] = wsrc[idx];
    __syncthreads();

    float A[13], Bv[13];
    #pragma unroll
    for (int mi = 0; mi < 13; ++mi) { A[mi] = 1.f; Bv[mi] = 0.f; }

    for (int ll = 0; ll < LC; ++ll) {
        const int gp = b * LL + c * LC + ll;
        const float e = e_ws[(size_t)gp * DD + d];
        const float a = a_ws[(size_t)gp * DD + d];
        const float* wl = w_lds + ll * MM + moff;
        #pragma unroll
        for (int mi = 0; mi < 13; ++mi) {
            if (mi < mcnt) {
                float w_ = wl[mi];
                float cc = fmaf(-w_, e, 1.f);
                A[mi] *= cc;
                Bv[mi] = fmaf(Bv[mi], cc, w_ * a);
            }
        }
    }

    float* Ao = A_ws + ((size_t)b * NC + c) * MM * DD + (size_t)moff * DD + d;
    float* Bo = B_ws + ((size_t)b * NC + c) * MM * DD + (size_t)moff * DD + d;
    #pragma unroll
    for (int mi = 0; mi < 13; ++mi) {
        if (mi < mcnt) { Ao[mi * DD] = A[mi]; Bo[mi * DD] = Bv[mi]; }
    }
}

// ---------------------------------------------------------------------------
// Kernel 2b: sequential composition over chunks; entry states in-place.
// ---------------------------------------------------------------------------
__global__ __launch_bounds__(256) void k_scanB(
    const float* __restrict__ Mv0,
    float* __restrict__ A_ws,            // in: A, out: Sentry
    const float* __restrict__ B_ws)
{
    const int g  = blockIdx.x * 256 + threadIdx.x;   // 0 .. B*M*D-1
    const int d  = g & (DD - 1);
    const int md = g >> 7;
    const int m  = md % MM;
    const int b  = md / MM;

    float S = Mv0[m * DD + d];
    const size_t base = ((size_t)b * NC * MM + m) * DD + d;
    #pragma unroll
    for (int c = 0; c < NC; ++c) {
        const size_t off = base + (size_t)c * MM * DD;
        const float Ac = A_ws[off];
        const float Bc = B_ws[off];
        A_ws[off] = S;                     // entry state of chunk c
        S = fmaf(Ac, S, Bc);
    }
}

// ---------------------------------------------------------------------------
// Kernel 2c: replay scan per (b, chunk); writes all Mv states and read.
// (measured: ~66 µs at 5.1 TB/s, ~85% of its stream floor)
// ---------------------------------------------------------------------------
__global__ __launch_bounds__(512) void k_scanC(
    const float* __restrict__ Sentry,     // == A_ws after k_scanB
    const float* __restrict__ w_ws, const float* __restrict__ e_ws,
    const float* __restrict__ a_ws,
    float* __restrict__ read_ws, float* __restrict__ out_Mv)
{
    __shared__ float w_lds[LC * MM];      // 4 KB
    __shared__ float red[2][4][DD];       // 4 KB

    const int b   = blockIdx.x / NC;
    const int c   = blockIdx.x % NC;
    const int tid = threadIdx.x;
    const int d   = tid & 127;
    const int g   = tid >> 7;
    int moff = g * 13; if (g == 3) moff = 38;
    const int mcnt = (g < 2) ? 13 : 12;

    const float* wsrc = w_ws + ((size_t)b * LL + c * LC) * MM;
    for (int idx = tid; idx < LC * MM; idx += 512) w_lds[idx] = wsrc[idx];

    float S[13];
    const float* Sp = Sentry + ((size_t)b * NC + c) * MM * DD + (size_t)moff * DD + d;
    #pragma unroll
    for (int mi = 0; mi < 13; ++mi)
        if (mi < mcnt) S[mi] = Sp[mi * DD];

    float* outb = out_Mv + (size_t)b * (LL + 1) * MM * DD;
    if (c == 0) {
        #pragma unroll
        for (int mi = 0; mi < 13; ++mi)
            if (mi < mcnt) outb[(moff + mi) * DD + d] = S[mi];  // init state
    }
    __syncthreads();

    for (int ll = 0; ll < LC; ++ll) {
        const int l  = c * LC + ll;
        const int gp = b * LL + l;
        const float e = e_ws[(size_t)gp * DD + d];
        const float a = a_ws[(size_t)gp * DD + d];
        const float* wl = w_lds + ll * MM + moff;

        float racc = 0.f;
        float* o = outb + (size_t)(l + 1) * MM * DD + d;
        #pragma unroll
        for (int mi = 0; mi < 13; ++mi) {
            if (mi < mcnt) {
                float w_ = wl[mi];
                racc = fmaf(w_, S[mi], racc);                // pre-update read
                S[mi] = fmaf(w_, fmaf(-S[mi], e, a), S[mi]); // S += w*(a - S*e)
                o[(moff + mi) * DD] = S[mi];
            }
        }
        red[ll & 1][g][d] = racc;
        __syncthreads();
        if (g == 0)
            read_ws[(size_t)gp * DD + d] =
                red[ll & 1][0][d] + red[ll & 1][1][d] +
                red[ll & 1][2][d] + red[ll & 1][3][d];
    }
}

// ---------------------------------------------------------------------------
// Kernel 3: f = tanh([read,k] @ f_W^T + f_b); p = sigmoid(f . p_W + p_b).
// One block = 16 positions, 128 threads. (R2-measured-best version)
// ---------------------------------------------------------------------------
__global__ __launch_bounds__(128) void k_fp(
    const int* __restrict__ q,
    const float* __restrict__ k_emb,
    const float* __restrict__ read_ws,
    const float* __restrict__ f_W, const float* __restrict__ f_b,
    const float* __restrict__ p_W, const float* __restrict__ p_b,
    float* __restrict__ out_p)
{
    __shared__ float cat[16][2 * DD];
    __shared__ float fv[16][DD];

    const int tid = threadIdx.x;
    const int p0  = blockIdx.x * 16;

    #pragma unroll
    for (int rr = 0; rr < 8; ++rr) {
        int idx = rr * 128 + tid;         // 0..1023 = 16 pos x 64 float4
        int pos = idx >> 6;
        int c4  = idx & 63;
        int gp  = p0 + pos;
        float4 val;
        if (c4 < 32) val = *(const float4*)(read_ws + (size_t)gp * DD + c4 * 4);
        else         val = *(const float4*)(k_emb + (size_t)q[gp] * DD + (c4 - 32) * 4);
        *(float4*)(&cat[pos][c4 * 4]) = val;
    }
    __syncthreads();

    const int i = tid;
    float acc[16];
    const float fb = f_b[i];
    #pragma unroll
    for (int p = 0; p < 16; ++p) acc[p] = fb;

    const float4* fw = (const float4*)(f_W + (size_t)i * (2 * DD));
    #pragma unroll 2
    for (int j4 = 0; j4 < 64; ++j4) {
        float4 wv = fw[j4];
        #pragma unroll
        for (int p = 0; p < 16; ++p) {
            const float* cp = &cat[p][j4 * 4];
            acc[p] = fmaf(wv.x, cp[0], acc[p]);
            acc[p] = fmaf(wv.y, cp[1], acc[p]);
            acc[p] = fmaf(wv.z, cp[2], acc[p]);
            acc[p] = fmaf(wv.w, cp[3], acc[p]);
        }
    }
    #pragma unroll
    for (int p = 0; p < 16; ++p) fv[p][i] = tanhf(acc[p]);
    __syncthreads();

    const int pos = tid >> 3;
    const int l8  = tid & 7;
    float partial = 0.f;
    #pragma unroll
    for (int ii = l8; ii < DD; ii += 8)
        partial = fmaf(fv[pos][ii], p_W[ii], partial);
    partial += __shfl_down(partial, 4, 64);
    partial += __shfl_down(partial, 2, 64);
    partial += __shfl_down(partial, 1, 64);
    if (l8 == 0)
        out_p[p0 + pos] = 1.f / (1.f + expf(-(partial + p_b[0])));
}

// ---------------------------------------------------------------------------
extern "C" void kernel_launch(void* const* d_in, const int* in_sizes, int n_in,
                              void* d_out, int out_size, void* d_ws, size_t ws_size,
                              hipStream_t stream)
{
    const int*   q     = (const int*)d_in[0];
    const int*   r     = (const int*)d_in[1];
    const float* k_emb = (const float*)d_in[2];
    const float* v_emb = (const float*)d_in[3];
    const float* Mk    = (const float*)d_in[4];
    const float* Mv0   = (const float*)d_in[5];
    const float* f_W   = (const float*)d_in[6];
    const float* f_b   = (const float*)d_in[7];
    const float* p_W   = (const float*)d_in[8];
    const float* p_b   = (const float*)d_in[9];
    const float* e_W   = (const float*)d_in[10];
    const float* e_b   = (const float*)d_in[11];
    const float* a_W   = (const float*)d_in[12];
    const float* a_b   = (const float*)d_in[13];

    float* out_p  = (float*)d_out;           // [B,L]
    float* out_Mv = out_p + NPOS;            // [B,L+1,M,D]

    float* w_ws    = (float*)d_ws;                         // NPOS*MM
    float* e_ws    = w_ws + (size_t)NPOS * MM;             // NPOS*DD
    float* a_ws    = e_ws + (size_t)NPOS * DD;             // NPOS*DD
    float* read_ws = a_ws + (size_t)NPOS * DD;             // NPOS*DD
    float* A_ws    = read_ws + (size_t)NPOS * DD;          // B*NC*MM*DD
    float* B_ws    = A_ws + (size_t)BB * NC * MM * DD;     // B*NC*MM*DD

    hipLaunchKernelGGL(k_wea2, dim3(1000), dim3(256), 0, stream,
                       q, r, k_emb, v_emb, Mk, e_W, e_b, a_W, a_b,
                       w_ws, e_ws, a_ws);
    hipLaunchKernelGGL(k_scanA, dim3(BB * NC), dim3(512), 0, stream,
                       w_ws, e_ws, a_ws, A_ws, B_ws);
    hipLaunchKernelGGL(k_scanB, dim3((BB * MM * DD) / 256), dim3(256), 0, stream,
                       Mv0, A_ws, B_ws);
    hipLaunchKernelGGL(k_scanC, dim3(BB * NC), dim3(512), 0, stream,
                       A_ws, w_ws, e_ws, a_ws, read_ws, out_Mv);
    hipLaunchKernelGGL(k_fp, dim3(NPOS / 16), dim3(128), 0, stream,
                       q, k_emb, read_ws, f_W, f_b, p_W, p_b, out_p);
}